// Round 1
// baseline (1103.032 us; speedup 1.0000x reference)
//
#include <hip/hip_runtime.h>
#include <math.h>

#define NG  16384
#define NN  32
#define DD  128
#define RR  32
#define OO  64
#define HHH 256

// M[o][r] = sum_h Wl[o][h] * V[h][r]   (collapses readout@Wl.T into pooled@M.T)
__global__ void precompute_M_kernel(const float* __restrict__ Wl,
                                    const float* __restrict__ V,
                                    float* __restrict__ M) {
    int t = blockIdx.x * blockDim.x + threadIdx.x;   // 0..2047
    int o = t >> 5;
    int r = t & 31;
    float s = 0.f;
#pragma unroll 8
    for (int hh = 0; hh < HHH; ++hh)
        s = fmaf(Wl[o * HHH + hh], V[hh * RR + r], s);
    M[o * RR + r] = s;
}

__device__ __forceinline__ void fma4(float4& a, float s, const float4& w) {
    a.x = fmaf(s, w.x, a.x);
    a.y = fmaf(s, w.y, a.y);
    a.z = fmaf(s, w.z, a.z);
    a.w = fmaf(s, w.w, a.w);
}

// One wave per graph (4 graphs sequentially per wave). No block barriers in the
// graph loop: each wave owns a private padded LDS chunk buffer.
__global__ __launch_bounds__(256, 4)
void gin_main_kernel(const float* __restrict__ hsrc,
                     const float* __restrict__ W,
                     const float* __restrict__ M,
                     const float* __restrict__ bl,
                     float* __restrict__ out) {
    __shared__ float sW[DD * RR];        // [d][r] row-major, 16 KB, block-shared
    __shared__ float sH[4][NN * 36];     // per-wave 32x32 d-chunk, row stride 36 (bank rotate)

    const int tid  = threadIdx.x;
    const int lane = tid & 63;
    const int wv   = tid >> 6;

    {   // stage W once (straight copy — same [d][r] flat layout)
        const float4* Wv  = (const float4*)W;
        float4*       sWv = (float4*)sW;
#pragma unroll
        for (int k = 0; k < 4; ++k) sWv[tid + k * 256] = Wv[tid + k * 256];
    }
    __syncthreads();   // only block-wide barrier

    const int rg = lane & 7;      // r-group: this lane covers r = rg*4 .. rg*4+3
    const int ng = lane >> 3;     // n-group: this lane covers n = ng, ng+8, ng+16, ng+24
    const int r0 = rg * 4;
    float* sHw = sH[wv];
    const int srow = lane >> 3;   // staging row-in-8-row-group
    const int sq   = lane & 7;    // staging quad within row
    const float* pWb = sW + r0;

    const int wave_global = blockIdx.x * 4 + wv;   // 0..4095
    const float blv = bl[lane];

#pragma unroll 1
    for (int gi = 0; gi < 4; ++gi) {
        const int g = wave_global * 4 + gi;
        const float* hg = hsrc + (size_t)g * (NN * DD);

        // prologue: load d-chunk 0 (32 rows x 32 d) into regs
        float4 v0 = *(const float4*)(hg + (0 * 8 + srow) * DD + sq * 4);
        float4 v1 = *(const float4*)(hg + (1 * 8 + srow) * DD + sq * 4);
        float4 v2 = *(const float4*)(hg + (2 * 8 + srow) * DD + sq * 4);
        float4 v3 = *(const float4*)(hg + (3 * 8 + srow) * DD + sq * 4);

        float4 acc0 = make_float4(0.f, 0.f, 0.f, 0.f);
        float4 acc1 = acc0, acc2 = acc0, acc3 = acc0;

#pragma unroll
        for (int c = 0; c < 4; ++c) {
            // commit chunk c to LDS (write quad = (srow+sq)&7 -> conflict-free)
            float* wb = sHw + srow * 36 + sq * 4;
            *(float4*)(wb + 0 * 8 * 36) = v0;
            *(float4*)(wb + 1 * 8 * 36) = v1;
            *(float4*)(wb + 2 * 8 * 36) = v2;
            *(float4*)(wb + 3 * 8 * 36) = v3;
            if (c < 3) {   // prefetch chunk c+1 while computing chunk c
                const float* gp = hg + (c + 1) * 32 + srow * DD + sq * 4;
                v0 = *(const float4*)(gp + 0 * 8 * DD);
                v1 = *(const float4*)(gp + 1 * 8 * DD);
                v2 = *(const float4*)(gp + 2 * 8 * DD);
                v3 = *(const float4*)(gp + 3 * 8 * DD);
            }
            const float* ph = sHw + ng * 36;
#pragma unroll
            for (int q = 0; q < 8; ++q) {
                const int d = c * 32 + q * 4;
                float4 w0 = *(const float4*)(pWb + (d + 0) * RR);
                float4 w1 = *(const float4*)(pWb + (d + 1) * RR);
                float4 w2 = *(const float4*)(pWb + (d + 2) * RR);
                float4 w3 = *(const float4*)(pWb + (d + 3) * RR);
                float4 h0 = *(const float4*)(ph + (0 * 8) * 36 + q * 4);
                float4 h1 = *(const float4*)(ph + (1 * 8) * 36 + q * 4);
                float4 h2 = *(const float4*)(ph + (2 * 8) * 36 + q * 4);
                float4 h3 = *(const float4*)(ph + (3 * 8) * 36 + q * 4);
                fma4(acc0, h0.x, w0); fma4(acc0, h0.y, w1); fma4(acc0, h0.z, w2); fma4(acc0, h0.w, w3);
                fma4(acc1, h1.x, w0); fma4(acc1, h1.y, w1); fma4(acc1, h1.z, w2); fma4(acc1, h1.w, w3);
                fma4(acc2, h2.x, w0); fma4(acc2, h2.y, w1); fma4(acc2, h2.z, w2); fma4(acc2, h2.w, w3);
                fma4(acc3, h3.x, w0); fma4(acc3, h3.y, w1); fma4(acc3, h3.z, w2); fma4(acc3, h3.w, w3);
            }
        }

        // pooled[r] = prod over all 32 n: lane-local x4, then butterfly over ng lanes
        float4 p;
        p.x = acc0.x * acc1.x * acc2.x * acc3.x;
        p.y = acc0.y * acc1.y * acc2.y * acc3.y;
        p.z = acc0.z * acc1.z * acc2.z * acc3.z;
        p.w = acc0.w * acc1.w * acc2.w * acc3.w;
#pragma unroll
        for (int m = 8; m <= 32; m <<= 1) {
            p.x *= __shfl_xor(p.x, m);
            p.y *= __shfl_xor(p.y, m);
            p.z *= __shfl_xor(p.z, m);
            p.w *= __shfl_xor(p.w, m);
        }

        // score[o = lane] = bl[lane] + sum_r pooled[r] * M[lane][r]
        const float4* Mv = (const float4*)(M + lane * RR);
        float s = blv;
#pragma unroll
        for (int rq = 0; rq < 8; ++rq) {
            float4 pq;                       // pooled quad rq lives (a.o.) in lane rq
            pq.x = __shfl(p.x, rq);
            pq.y = __shfl(p.y, rq);
            pq.z = __shfl(p.z, rq);
            pq.w = __shfl(p.w, rq);
            float4 m4 = Mv[rq];
            s = fmaf(pq.x, m4.x, s);
            s = fmaf(pq.y, m4.y, s);
            s = fmaf(pq.z, m4.z, s);
            s = fmaf(pq.w, m4.w, s);
        }
        out[(size_t)g * OO + lane] = s;
    }
}

extern "C" void kernel_launch(void* const* d_in, const int* in_sizes, int n_in,
                              void* d_out, int out_size, void* d_ws, size_t ws_size,
                              hipStream_t stream) {
    const float* h  = (const float*)d_in[0];   // [16384,32,128]
    const float* W  = (const float*)d_in[1];   // [128,32]
    const float* V  = (const float*)d_in[2];   // [256,32]
    const float* Wl = (const float*)d_in[3];   // [64,256]
    const float* bl = (const float*)d_in[4];   // [64]
    float* out = (float*)d_out;                // [16384,64]
    float* M   = (float*)d_ws;                 // [64,32] scratch

    precompute_M_kernel<<<8, 256, 0, stream>>>(Wl, V, M);
    gin_main_kernel<<<1024, 256, 0, stream>>>(h, W, M, bl, out);
}

// Round 2
// 696.522 us; speedup vs baseline: 1.5836x; 1.5836x over previous
//
#include <hip/hip_runtime.h>
#include <math.h>

#define NG  16384
#define NN  32
#define DD  128
#define RR  32
#define OO  64
#define HHH 256

// M[o][r] = sum_h Wl[o][h] * V[h][r]   (collapses readout@Wl.T into pooled@M.T)
__global__ void precompute_M_kernel(const float* __restrict__ Wl,
                                    const float* __restrict__ V,
                                    float* __restrict__ M) {
    int t = blockIdx.x * blockDim.x + threadIdx.x;   // 0..2047
    int o = t >> 5;
    int r = t & 31;
    float s = 0.f;
#pragma unroll 8
    for (int hh = 0; hh < HHH; ++hh)
        s = fmaf(Wl[o * HHH + hh], V[hh * RR + r], s);
    M[o * RR + r] = s;
}

__device__ __forceinline__ void fma4(float4& a, float s, const float4& w) {
    a.x = fmaf(s, w.x, a.x);
    a.y = fmaf(s, w.y, a.y);
    a.z = fmaf(s, w.z, a.z);
    a.w = fmaf(s, w.w, a.w);
}

// One wave per graph (4 graphs sequentially per wave). No block barriers in the
// graph loop: each wave owns a private padded LDS chunk buffer.
// launch_bounds(256,2): cap 256 VGPRs — R1's (256,4) capped at 64 VGPRs and
// spilled ~1.3 GB to scratch (WRITE_SIZE 1.32e6 KB). LDS (34 KB) limits us to
// 4 blocks/CU regardless, so the looser VGPR cap costs nothing.
__global__ __launch_bounds__(256, 2)
void gin_main_kernel(const float* __restrict__ hsrc,
                     const float* __restrict__ W,
                     const float* __restrict__ M,
                     const float* __restrict__ bl,
                     float* __restrict__ out) {
    __shared__ float sW[DD * RR];        // [d][r] row-major, 16 KB, block-shared
    __shared__ float sH[4][NN * 36];     // per-wave 32x32 d-chunk, row stride 36 (bank rotate)

    const int tid  = threadIdx.x;
    const int lane = tid & 63;
    const int wv   = tid >> 6;

    {   // stage W once (straight copy — same [d][r] flat layout)
        const float4* Wv  = (const float4*)W;
        float4*       sWv = (float4*)sW;
#pragma unroll
        for (int k = 0; k < 4; ++k) sWv[tid + k * 256] = Wv[tid + k * 256];
    }
    __syncthreads();   // only block-wide barrier

    const int rg = lane & 7;      // r-group: this lane covers r = rg*4 .. rg*4+3
    const int ng = lane >> 3;     // n-group: this lane covers n = ng, ng+8, ng+16, ng+24
    const int r0 = rg * 4;
    float* sHw = sH[wv];
    const int srow = lane >> 3;   // staging row-in-8-row-group
    const int sq   = lane & 7;    // staging quad within row
    const float* pWb = sW + r0;

    const int wave_global = blockIdx.x * 4 + wv;   // 0..4095
    const float blv = bl[lane];

#pragma unroll 1
    for (int gi = 0; gi < 4; ++gi) {
        const int g = wave_global * 4 + gi;
        const float* hg = hsrc + (size_t)g * (NN * DD);

        // prologue: load d-chunk 0 (32 rows x 32 d) into regs
        float4 v0 = *(const float4*)(hg + (0 * 8 + srow) * DD + sq * 4);
        float4 v1 = *(const float4*)(hg + (1 * 8 + srow) * DD + sq * 4);
        float4 v2 = *(const float4*)(hg + (2 * 8 + srow) * DD + sq * 4);
        float4 v3 = *(const float4*)(hg + (3 * 8 + srow) * DD + sq * 4);

        float4 acc0 = make_float4(0.f, 0.f, 0.f, 0.f);
        float4 acc1 = acc0, acc2 = acc0, acc3 = acc0;

#pragma unroll
        for (int c = 0; c < 4; ++c) {
            // commit chunk c to LDS (write quad = (srow+sq)&7 -> conflict-free)
            float* wb = sHw + srow * 36 + sq * 4;
            *(float4*)(wb + 0 * 8 * 36) = v0;
            *(float4*)(wb + 1 * 8 * 36) = v1;
            *(float4*)(wb + 2 * 8 * 36) = v2;
            *(float4*)(wb + 3 * 8 * 36) = v3;
            if (c < 3) {   // prefetch chunk c+1 while computing chunk c
                const float* gp = hg + (c + 1) * 32 + srow * DD + sq * 4;
                v0 = *(const float4*)(gp + 0 * 8 * DD);
                v1 = *(const float4*)(gp + 1 * 8 * DD);
                v2 = *(const float4*)(gp + 2 * 8 * DD);
                v3 = *(const float4*)(gp + 3 * 8 * DD);
            }
            const float* ph = sHw + ng * 36;
#pragma unroll
            for (int q = 0; q < 8; ++q) {
                const int d = c * 32 + q * 4;
                float4 w0 = *(const float4*)(pWb + (d + 0) * RR);
                float4 w1 = *(const float4*)(pWb + (d + 1) * RR);
                float4 w2 = *(const float4*)(pWb + (d + 2) * RR);
                float4 w3 = *(const float4*)(pWb + (d + 3) * RR);
                float4 h0 = *(const float4*)(ph + (0 * 8) * 36 + q * 4);
                float4 h1 = *(const float4*)(ph + (1 * 8) * 36 + q * 4);
                float4 h2 = *(const float4*)(ph + (2 * 8) * 36 + q * 4);
                float4 h3 = *(const float4*)(ph + (3 * 8) * 36 + q * 4);
                fma4(acc0, h0.x, w0); fma4(acc0, h0.y, w1); fma4(acc0, h0.z, w2); fma4(acc0, h0.w, w3);
                fma4(acc1, h1.x, w0); fma4(acc1, h1.y, w1); fma4(acc1, h1.z, w2); fma4(acc1, h1.w, w3);
                fma4(acc2, h2.x, w0); fma4(acc2, h2.y, w1); fma4(acc2, h2.z, w2); fma4(acc2, h2.w, w3);
                fma4(acc3, h3.x, w0); fma4(acc3, h3.y, w1); fma4(acc3, h3.z, w2); fma4(acc3, h3.w, w3);
            }
        }

        // pooled[r] = prod over all 32 n: lane-local x4, then butterfly over ng lanes
        float4 p;
        p.x = acc0.x * acc1.x * acc2.x * acc3.x;
        p.y = acc0.y * acc1.y * acc2.y * acc3.y;
        p.z = acc0.z * acc1.z * acc2.z * acc3.z;
        p.w = acc0.w * acc1.w * acc2.w * acc3.w;
#pragma unroll
        for (int m = 8; m <= 32; m <<= 1) {
            p.x *= __shfl_xor(p.x, m);
            p.y *= __shfl_xor(p.y, m);
            p.z *= __shfl_xor(p.z, m);
            p.w *= __shfl_xor(p.w, m);
        }

        // score[o = lane] = bl[lane] + sum_r pooled[r] * M[lane][r]
        const float4* Mv = (const float4*)(M + lane * RR);
        float s = blv;
#pragma unroll
        for (int rq = 0; rq < 8; ++rq) {
            float4 pq;                       // pooled quad rq lives (a.o.) in lane rq
            pq.x = __shfl(p.x, rq);
            pq.y = __shfl(p.y, rq);
            pq.z = __shfl(p.z, rq);
            pq.w = __shfl(p.w, rq);
            float4 m4 = Mv[rq];
            s = fmaf(pq.x, m4.x, s);
            s = fmaf(pq.y, m4.y, s);
            s = fmaf(pq.z, m4.z, s);
            s = fmaf(pq.w, m4.w, s);
        }
        out[(size_t)g * OO + lane] = s;
    }
}

extern "C" void kernel_launch(void* const* d_in, const int* in_sizes, int n_in,
                              void* d_out, int out_size, void* d_ws, size_t ws_size,
                              hipStream_t stream) {
    const float* h  = (const float*)d_in[0];   // [16384,32,128]
    const float* W  = (const float*)d_in[1];   // [128,32]
    const float* V  = (const float*)d_in[2];   // [256,32]
    const float* Wl = (const float*)d_in[3];   // [64,256]
    const float* bl = (const float*)d_in[4];   // [64]
    float* out = (float*)d_out;                // [16384,64]
    float* M   = (float*)d_ws;                 // [64,32] scratch

    precompute_M_kernel<<<8, 256, 0, stream>>>(Wl, V, M);
    gin_main_kernel<<<1024, 256, 0, stream>>>(h, W, M, bl, out);
}

// Round 3
// 388.226 us; speedup vs baseline: 2.8412x; 1.7941x over previous
//
#include <hip/hip_runtime.h>
#include <math.h>

#define NG  16384
#define NN  32
#define DD  128
#define RR  32
#define OO  64
#define HHH 256

// M[o][r] = sum_h Wl[o][h] * V[h][r]   (collapses readout@Wl.T into pooled@M.T)
__global__ void precompute_M_kernel(const float* __restrict__ Wl,
                                    const float* __restrict__ V,
                                    float* __restrict__ M) {
    int t = blockIdx.x * blockDim.x + threadIdx.x;   // 0..2047
    int o = t >> 5;
    int r = t & 31;
    float s = 0.f;
#pragma unroll 8
    for (int hh = 0; hh < HHH; ++hh)
        s = fmaf(Wl[o * HHH + hh], V[hh * RR + r], s);
    M[o * RR + r] = s;
}

__device__ __forceinline__ void fma4(float4& a, float s, const float4& w) {
    a.x = fmaf(s, w.x, a.x);
    a.y = fmaf(s, w.y, a.y);
    a.z = fmaf(s, w.z, a.z);
    a.w = fmaf(s, w.w, a.w);
}

typedef const float __attribute__((address_space(1))) gfloat;
typedef float       __attribute__((address_space(3))) lfloat;

// One wave per graph (4 graphs sequentially per wave), no block barriers in
// the hot loop. h staging: global_load_lds 16B/lane into a per-wave buffer
// with XOR-rotated quads (element (n,sq) at float offset
// (n>>3)*256 + (n&7)*32 + ((sq-n)&7)*4), so reads of h[8k+ng][quad q] hit
// bank-quad (q-ng)&7 -> conflict-free without padding. No long-lived
// registers -> no spill (R1/R2 spilled 1.3GB/334MB via cross-chunk VGPR
// prefetch; WRITE_SIZE was the tell).
__global__ __launch_bounds__(256, 2)
void gin_main_kernel(const float* __restrict__ hsrc,
                     const float* __restrict__ W,
                     const float* __restrict__ M,
                     const float* __restrict__ bl,
                     float* __restrict__ out) {
    __shared__ float sW[DD * RR];        // [d][r] row-major, 16 KB, block-shared
    __shared__ float sH[4][NN * 32];     // per-wave 32x32 chunk, 4 KB each, XOR layout

    const int tid  = threadIdx.x;
    const int lane = tid & 63;
    const int wv   = tid >> 6;

    {   // stage W once (straight copy — same [d][r] flat layout)
        const float4* Wv  = (const float4*)W;
        float4*       sWv = (float4*)sW;
#pragma unroll
        for (int k = 0; k < 4; ++k) sWv[tid + k * 256] = Wv[tid + k * 256];
    }
    __syncthreads();   // only block-wide barrier

    const int rg = lane & 7;      // r-group: this lane covers r = rg*4 .. rg*4+3
    const int ng = lane >> 3;     // n-group: this lane covers n = ng, ng+8, ng+16, ng+24
    const int r0 = rg * 4;
    float* sHw = sH[wv];
    const int rowl = lane >> 3;   // staging row within 8-row group
    const int tq   = lane & 7;    // staging quad slot
    const float* pWb = sW + r0;

    const int wave_global = blockIdx.x * 4 + wv;   // 0..4095
    const float blv = bl[lane];

#pragma unroll 1
    for (int gi = 0; gi < 4; ++gi) {
        const int g = wave_global * 4 + gi;
        const float* hg = hsrc + (size_t)g * (NN * DD);

        float4 acc0 = make_float4(0.f, 0.f, 0.f, 0.f);
        float4 acc1 = acc0, acc2 = acc0, acc3 = acc0;

#pragma unroll
        for (int c = 0; c < 4; ++c) {
            // stage chunk c (32 rows x 32 d-floats) via async global->LDS
#pragma unroll
            for (int l = 0; l < 4; ++l) {
                const int row = l * 8 + rowl;
                const int sq  = (tq + row) & 7;            // XOR-rotate quads
                const float* gp = hg + row * DD + c * 32 + sq * 4;
                __builtin_amdgcn_global_load_lds((gfloat*)gp,
                                                 (lfloat*)(sHw + l * 256),
                                                 16, 0, 0);
            }
            asm volatile("s_waitcnt vmcnt(0)" ::: "memory");

            const float* ph = sHw + ng * 32;
#pragma unroll
            for (int q = 0; q < 8; ++q) {
                const int d = c * 32 + q * 4;
                const int hq = ((q - ng) & 7) * 4;         // rotated quad offset
                float4 w0 = *(const float4*)(pWb + (d + 0) * RR);
                float4 w1 = *(const float4*)(pWb + (d + 1) * RR);
                float4 w2 = *(const float4*)(pWb + (d + 2) * RR);
                float4 w3 = *(const float4*)(pWb + (d + 3) * RR);
                float4 h0 = *(const float4*)(ph + 0 * 256 + hq);
                float4 h1 = *(const float4*)(ph + 1 * 256 + hq);
                float4 h2 = *(const float4*)(ph + 2 * 256 + hq);
                float4 h3 = *(const float4*)(ph + 3 * 256 + hq);
                fma4(acc0, h0.x, w0); fma4(acc0, h0.y, w1); fma4(acc0, h0.z, w2); fma4(acc0, h0.w, w3);
                fma4(acc1, h1.x, w0); fma4(acc1, h1.y, w1); fma4(acc1, h1.z, w2); fma4(acc1, h1.w, w3);
                fma4(acc2, h2.x, w0); fma4(acc2, h2.y, w1); fma4(acc2, h2.z, w2); fma4(acc2, h2.w, w3);
                fma4(acc3, h3.x, w0); fma4(acc3, h3.y, w1); fma4(acc3, h3.z, w2); fma4(acc3, h3.w, w3);
            }
        }

        // pooled[r] = prod over all 32 n: lane-local x4, then butterfly over ng lanes
        float4 p;
        p.x = acc0.x * acc1.x * acc2.x * acc3.x;
        p.y = acc0.y * acc1.y * acc2.y * acc3.y;
        p.z = acc0.z * acc1.z * acc2.z * acc3.z;
        p.w = acc0.w * acc1.w * acc2.w * acc3.w;
#pragma unroll
        for (int m = 8; m <= 32; m <<= 1) {
            p.x *= __shfl_xor(p.x, m);
            p.y *= __shfl_xor(p.y, m);
            p.z *= __shfl_xor(p.z, m);
            p.w *= __shfl_xor(p.w, m);
        }

        // score[o = lane] = bl[lane] + sum_r pooled[r] * M[lane][r]
        const float4* Mv = (const float4*)(M + lane * RR);
        float s = blv;
#pragma unroll
        for (int rq = 0; rq < 8; ++rq) {
            float4 pq;                       // pooled quad rq lives (a.o.) in lane rq
            pq.x = __shfl(p.x, rq);
            pq.y = __shfl(p.y, rq);
            pq.z = __shfl(p.z, rq);
            pq.w = __shfl(p.w, rq);
            float4 m4 = Mv[rq];
            s = fmaf(pq.x, m4.x, s);
            s = fmaf(pq.y, m4.y, s);
            s = fmaf(pq.z, m4.z, s);
            s = fmaf(pq.w, m4.w, s);
        }
        out[(size_t)g * OO + lane] = s;
    }
}

extern "C" void kernel_launch(void* const* d_in, const int* in_sizes, int n_in,
                              void* d_out, int out_size, void* d_ws, size_t ws_size,
                              hipStream_t stream) {
    const float* h  = (const float*)d_in[0];   // [16384,32,128]
    const float* W  = (const float*)d_in[1];   // [128,32]
    const float* V  = (const float*)d_in[2];   // [256,32]
    const float* Wl = (const float*)d_in[3];   // [64,256]
    const float* bl = (const float*)d_in[4];   // [64]
    float* out = (float*)d_out;                // [16384,64]
    float* M   = (float*)d_ws;                 // [64,32] scratch

    precompute_M_kernel<<<8, 256, 0, stream>>>(Wl, V, M);
    gin_main_kernel<<<1024, 256, 0, stream>>>(h, W, M, bl, out);
}